// Round 8
// baseline (309.009 us; speedup 1.0000x reference)
//
#include <hip/hip_runtime.h>

typedef short s8v __attribute__((ext_vector_type(8)));   // 8 bf16 (guide §3 frag_ab)
typedef float f4v __attribute__((ext_vector_type(4)));   // MFMA accumulator
typedef int   i4v __attribute__((ext_vector_type(4)));   // 16B int view for reg pin

#define LOG2E 1.4426950408889634f
#define LN2   0.6931471805599453f

// Raw barrier: LDS visibility only (lgkmcnt), vmcnt floats -> global prefetch stays async.
#define SYNC_LDS() __asm__ __volatile__("s_waitcnt lgkmcnt(0)\n\ts_barrier" ::: "memory")

__device__ __forceinline__ float fast_exp2(float x) {
#if __has_builtin(__builtin_amdgcn_exp2f)
    return __builtin_amdgcn_exp2f(x);
#else
    return exp2f(x);
#endif
}

// f32 -> bf16 (RNE). bf16 keeps the full f32 exponent range: no under/overflow.
__device__ __forceinline__ unsigned short f2bf(float x) {
    unsigned int u = __float_as_uint(x);
    return (unsigned short)((u + 0x7fffu + ((u >> 16) & 1u)) >> 16);
}

// One block per batch element b; thread j owns output column j (= 64*wave + lane).
// Exp-space linear recursion, matvec on MFMA. A = u chunk (all row-groups equal),
// B = E slice resident in VGPRs/AGPRs. One raw barrier per step; u renormalized by
// the exponent of the previous stored u(0) (memoryless, exact pow2, C-accounted).
// R8: accumulator chains split 8->4 deep; scale s hoisted before the MFMA block.
__launch_bounds__(256, 1)
__global__ void crf_main(const float* __restrict__ emissions,
                         const int*   __restrict__ tags,
                         const float* __restrict__ mask,
                         const float* __restrict__ trans,
                         float*       __restrict__ ws) {
    const int T = 512, N = 256;
    const int b  = blockIdx.x;
    const int j  = threadIdx.x;
    const int l  = j & 63;          // lane
    const int w  = j >> 6;          // wave
    const int lg = l >> 4;          // 16-lane group (K sub-chunk)
    const int ll = l & 15;          // position in group (N dim)

    __shared__ alignas(16) unsigned short u_lds[2][256];  // u as bf16, double-buffered
    __shared__ float cm2_lds[256];
    __shared__ float red[256];

    // ---- per-column log2-max of trans (thread j -> column j, coalesced) ----
    const float* tcol = trans + j;
    float cmax = -1e30f;
    #pragma unroll 8
    for (int i = 0; i < N; ++i) cmax = fmaxf(cmax, tcol[i * N]);
    cm2_lds[j] = cmax * LOG2E;
    __syncthreads();
    const float cm2 = cm2_lds[j];   // own column's, kept in a register

    // ---- E fragments (B operand), registers for the whole kernel ----
    // tile c: cols 64w+16c+ll ; chunk q: k = 32q + 8*lg + e  (same kmap as u frags:
    // any HW k-permutation within (lg,e) slots cancels between A and B).
    s8v Efr[4][8];
    #pragma unroll
    for (int c = 0; c < 4; ++c) {
        const int   col = 64 * w + 16 * c + ll;
        const float cc  = cm2_lds[col];
        #pragma unroll
        for (int q = 0; q < 8; ++q) {
            s8v e;
            #pragma unroll
            for (int el = 0; el < 8; ++el) {
                const int k = 32 * q + 8 * lg + el;
                e[el] = (short)f2bf(fast_exp2(trans[k * N + col] * LOG2E - cc));
            }
            i4v ei = __builtin_bit_cast(i4v, e);       // keep compiler honest about
            asm volatile("" : "+v"(ei));               // VGPR residency
            Efr[c][q] = __builtin_bit_cast(s8v, ei);
        }
    }

    // ---- init: u_0 = bf16(2^(log2e * emit[b,0,j])), C = 0 ----
    const float* em_base = emissions + ((size_t)b * T) * N + j;
    float v = fast_exp2(em_base[0] * LOG2E);           // |log2 v| <= ~10: fits bf16
    float C = 0.f;
    float em_next  = em_base[N];
    float em_next2 = em_base[2 * N];
    u_lds[0][j] = f2bf(v);
    SYNC_LDS();

    for (int t = 1; t < T; ++t) {
        const int pb = (t - 1) & 1;
        // u fragments: chunk q -> 16B at byte 64q + 16*lg (16-lane broadcast groups,
        // distinct banks across groups: conflict-free) + u(0) broadcast (free)
        const uint4* ub = (const uint4*)u_lds[pb];
        s8v ua[8];
        #pragma unroll
        for (int q = 0; q < 8; ++q)
            ua[q] = __builtin_bit_cast(s8v, ub[4 * q + lg]);
        const unsigned int u0b = u_lds[pb][0];         // exponent reference, same-addr read

        float em = em_next;
        em_next = em_next2;
        if (t + 2 < T) em_next2 = em_base[(size_t)(t + 2) * N];  // vmcnt never drained

        // ---- scale hoisted off the tail: everything except vraw is known now ----
        const int   e    = (int)((u0b >> 7) & 0xffu);   // biased bf16 exp of prev u(0)
        const float r    = __int_as_float((250 - e) << 23);  // 2^-(e-127+4), exact
        const float gain = fast_exp2(fmaf(em, LOG2E, cm2));  // emit + colmax fold-in
        const float s    = gain * r;

        // ---- MFMA block: 4 tiles x 2 half-chains (depth 4) ----
        f4v dA0 = {0.f,0.f,0.f,0.f}, dA1 = dA0, dA2 = dA0, dA3 = dA0;
        f4v dB0 = dA0, dB1 = dA0, dB2 = dA0, dB3 = dA0;
        #pragma unroll
        for (int q = 0; q < 4; ++q) {
            dA0 = __builtin_amdgcn_mfma_f32_16x16x32_bf16(ua[q], Efr[0][q], dA0, 0, 0, 0);
            dA1 = __builtin_amdgcn_mfma_f32_16x16x32_bf16(ua[q], Efr[1][q], dA1, 0, 0, 0);
            dA2 = __builtin_amdgcn_mfma_f32_16x16x32_bf16(ua[q], Efr[2][q], dA2, 0, 0, 0);
            dA3 = __builtin_amdgcn_mfma_f32_16x16x32_bf16(ua[q], Efr[3][q], dA3, 0, 0, 0);
            dB0 = __builtin_amdgcn_mfma_f32_16x16x32_bf16(ua[q+4], Efr[0][q+4], dB0, 0, 0, 0);
            dB1 = __builtin_amdgcn_mfma_f32_16x16x32_bf16(ua[q+4], Efr[1][q+4], dB1, 0, 0, 0);
            dB2 = __builtin_amdgcn_mfma_f32_16x16x32_bf16(ua[q+4], Efr[2][q+4], dB2, 0, 0, 0);
            dB3 = __builtin_amdgcn_mfma_f32_16x16x32_bf16(ua[q+4], Efr[3][q+4], dB3, 0, 0, 0);
        }
        // thread j's column sits in tile lg, slot ll; rows all equal -> element 0.
        float vraw = ((lg == 0) ? dA0[0] : (lg == 1) ? dA1[0] : (lg == 2) ? dA2[0] : dA3[0])
                   + ((lg == 0) ? dB0[0] : (lg == 1) ? dB1[0] : (lg == 2) ? dB2[0] : dB3[0]);

        if (t < T - 1) {
            C += (float)(e - 123);
            u_lds[t & 1][j] = f2bf(vraw * s);           // short tail: mul, cvt, write
        } else {
            v = vraw * gain;                            // final step keeps unrenormed v
        }
        SYNC_LDS();
    }

    // ---- Z_b = ln2 * (C + log2(sum_j v_j)), v in scale 2^-C ----
    red[j] = v;
    __syncthreads();
    #pragma unroll
    for (int s2 = 128; s2 > 0; s2 >>= 1) {
        if (j < s2) red[j] += red[j + s2];
        __syncthreads();
    }
    float Z = (C + log2f(red[0])) * LN2;
    __syncthreads();   // everyone done reading red[0] before reuse

    // ---- gold score (gather) ----
    float gp = 0.f;
    const int*   tg  = tags + (size_t)b * T;
    const float* mk  = mask + (size_t)b * T;
    const float* emb = emissions + ((size_t)b * T) * N;
    for (int t = 1 + j; t < T; t += 256) {
        int tt = tg[t], tp = tg[t - 1];
        gp += (emb[(size_t)t * N + tt] + trans[(size_t)tp * N + tt]) * mk[t];
    }
    if (j == 0) gp += emb[tg[0]];
    red[j] = gp;
    __syncthreads();
    #pragma unroll
    for (int s2 = 128; s2 > 0; s2 >>= 1) {
        if (j < s2) red[j] += red[j + s2];
        __syncthreads();
    }
    if (j == 0) ws[b] = Z - red[0];
}

// Deterministic mean over the 128 per-batch results.
__global__ void crf_finalize(const float* __restrict__ ws, float* __restrict__ out) {
    int l = threadIdx.x;                 // 64 threads, one wave
    float s = ws[l] + ws[l + 64];
    #pragma unroll
    for (int d = 32; d > 0; d >>= 1) s += __shfl_down(s, d);
    if (l == 0) out[0] = s * (1.0f / 128.0f);
}

extern "C" void kernel_launch(void* const* d_in, const int* in_sizes, int n_in,
                              void* d_out, int out_size, void* d_ws, size_t ws_size,
                              hipStream_t stream) {
    const float* emissions = (const float*)d_in[0];
    const int*   tags      = (const int*)  d_in[1];
    const float* mask      = (const float*)d_in[2];
    const float* trans     = (const float*)d_in[3];
    float* out = (float*)d_out;
    float* ws  = (float*)d_ws;           // 128 floats of scratch

    crf_main<<<dim3(128), dim3(256), 0, stream>>>(emissions, tags, mask, trans, ws);
    crf_finalize<<<dim3(1), dim3(64), 0, stream>>>(ws, out);
}